// Round 1
// baseline (62.311 us; speedup 1.0000x reference)
//
#include <hip/hip_runtime.h>

#define NUM_EXPERTS 8
#define TOPK 2
#define H 2048
#define H4 512            // H / 4 (float4 columns)
#define NTOK 16384        // 4 * 4096 tokens
#define TOK_PER_WAVE 4
#define WAVES_PER_BLOCK 4
#define TOK_PER_BLOCK (TOK_PER_WAVE * WAVES_PER_BLOCK)   // 16
#define AUX_COEF 0.01f

// Main kernel: one wave computes 4 tokens' logits (8 experts each),
// then softmax + top-2 + renorm, writes outputs, accumulates aux-loss stats.
__global__ __launch_bounds__(256, 4)
void router_main(const float* __restrict__ hs, const float* __restrict__ gw,
                 float* __restrict__ out, float* __restrict__ ws)
{
    __shared__ float s_psum[NUM_EXPERTS];
    __shared__ float s_cnt[NUM_EXPERTS];
    const int tid = threadIdx.x;
    if (tid < NUM_EXPERTS) { s_psum[tid] = 0.f; s_cnt[tid] = 0.f; }
    __syncthreads();

    const int wave = tid >> 6;
    const int lane = tid & 63;
    const int tok0 = blockIdx.x * TOK_PER_BLOCK + wave * TOK_PER_WAVE;

    const float4* __restrict__ hs4 = (const float4*)hs;
    const float4* __restrict__ gw4 = (const float4*)gw;

    float acc[TOK_PER_WAVE][NUM_EXPERTS];
    #pragma unroll
    for (int t = 0; t < TOK_PER_WAVE; ++t)
        #pragma unroll
        for (int e = 0; e < NUM_EXPERTS; ++e) acc[t][e] = 0.f;

    // 512 float4 columns per token; lane covers col = it*64 + lane, it = 0..7
    #pragma unroll 2
    for (int it = 0; it < 8; ++it) {
        const int col = it * 64 + lane;
        float4 h[TOK_PER_WAVE];
        #pragma unroll
        for (int t = 0; t < TOK_PER_WAVE; ++t)
            h[t] = hs4[(size_t)(tok0 + t) * H4 + col];
        #pragma unroll
        for (int e = 0; e < NUM_EXPERTS; ++e) {
            const float4 g = gw4[e * H4 + col];
            #pragma unroll
            for (int t = 0; t < TOK_PER_WAVE; ++t)
                acc[t][e] += h[t].x * g.x + h[t].y * g.y
                           + h[t].z * g.z + h[t].w * g.w;
        }
    }

    // full-wave butterfly reduce: every lane ends with the complete dot
    #pragma unroll
    for (int t = 0; t < TOK_PER_WAVE; ++t) {
        #pragma unroll
        for (int e = 0; e < NUM_EXPERTS; ++e) {
            float v = acc[t][e];
            #pragma unroll
            for (int s = 32; s > 0; s >>= 1) v += __shfl_xor(v, s, 64);
            acc[t][e] = v;
        }
    }

    #pragma unroll
    for (int t = 0; t < TOK_PER_WAVE; ++t) {
        const int tok = tok0 + t;
        // softmax over 8 logits
        float m = acc[t][0];
        #pragma unroll
        for (int e = 1; e < NUM_EXPERTS; ++e) m = fmaxf(m, acc[t][e]);
        float p[NUM_EXPERTS];
        float s = 0.f;
        #pragma unroll
        for (int e = 0; e < NUM_EXPERTS; ++e) { p[e] = __expf(acc[t][e] - m); s += p[e]; }
        const float inv = 1.f / s;

        // top-2 on probs; strict '>' keeps the lowest index on ties (lax.top_k)
        float v0 = -1.f; int i0 = 0;
        #pragma unroll
        for (int e = 0; e < NUM_EXPERTS; ++e) { if (p[e] > v0) { v0 = p[e]; i0 = e; } }
        float v1 = -1.f; int i1 = 0;
        #pragma unroll
        for (int e = 0; e < NUM_EXPERTS; ++e) { if (e != i0 && p[e] > v1) { v1 = p[e]; i1 = e; } }

        if (lane == 0) {
            const float wsum = v0 + v1;
            out[tok * 2 + 0] = v0 / wsum;
            out[tok * 2 + 1] = v1 / wsum;
            out[2 * NTOK + tok * 2 + 0] = (float)i0;
            out[2 * NTOK + tok * 2 + 1] = (float)i1;
            #pragma unroll
            for (int e = 0; e < NUM_EXPERTS; ++e) atomicAdd(&s_psum[e], p[e] * inv);
            atomicAdd(&s_cnt[i0], 1.f);
            atomicAdd(&s_cnt[i1], 1.f);
        }
    }

    __syncthreads();
    if (tid < NUM_EXPERTS) {
        atomicAdd(&ws[tid], s_psum[tid]);
        atomicAdd(&ws[NUM_EXPERTS + tid], s_cnt[tid]);
    }
}

// Final tiny kernel: aux = E * sum(expert_frac * router_frac) * coef
__global__ void router_aux(const float* __restrict__ ws, float* __restrict__ out)
{
    if (threadIdx.x == 0 && blockIdx.x == 0) {
        float s = 0.f;
        #pragma unroll
        for (int e = 0; e < NUM_EXPERTS; ++e) {
            const float ef = ws[NUM_EXPERTS + e] / (float)(NTOK * TOPK);
            const float rf = ws[e] / (float)NTOK;
            s += ef * rf;
        }
        out[4 * NTOK] = (float)NUM_EXPERTS * s * AUX_COEF;
    }
}

extern "C" void kernel_launch(void* const* d_in, const int* in_sizes, int n_in,
                              void* d_out, int out_size, void* d_ws, size_t ws_size,
                              hipStream_t stream)
{
    const float* hs = (const float*)d_in[0];   // [4,4096,2048] f32
    const float* gw = (const float*)d_in[1];   // [8,2048] f32
    float* out = (float*)d_out;                // 32768 rw | 32768 idx | 1 aux
    float* ws  = (float*)d_ws;                 // 16 floats of accumulators

    hipMemsetAsync(d_ws, 0, 2 * NUM_EXPERTS * sizeof(float), stream);
    hipLaunchKernelGGL(router_main, dim3(NTOK / TOK_PER_BLOCK), dim3(256), 0, stream,
                       hs, gw, out, ws);
    hipLaunchKernelGGL(router_aux, dim3(1), dim3(64), 0, stream, ws, out);
}